// Round 15
// baseline (344.853 us; speedup 1.0000x reference)
//
#include <hip/hip_runtime.h>
#include <hip/hip_bf16.h>

#define NTOK 4096   // B*T
#define HDIM 1024
#define IDIM 2048
#define NEXP 8
#define RBLK 16     // tokens per routing block

typedef __attribute__((ext_vector_type(8))) short short8;
typedef __attribute__((ext_vector_type(4))) short short4b;
typedef __attribute__((ext_vector_type(4))) float f32x4;
typedef unsigned short ushort_t;

__device__ inline ushort_t f2bf(float f) {
    union { float f; unsigned u; } v; v.f = f;
    unsigned r = v.u + 0x7FFFu + ((v.u >> 16) & 1u);
    return (ushort_t)(r >> 16);
}
__device__ inline float bf2f(ushort_t h) {
    union { unsigned u; float f; } v; v.u = ((unsigned)h) << 16;
    return v.f;
}

#define GPTR(p) ((const __attribute__((address_space(1))) void*)(p))
#define LPTR(p) ((__attribute__((address_space(3))) void*)(p))

// granule swizzle for [*][32] bf16 LDS tiles: slot c holds source granule (c - f(r)) & 3
__device__ inline int frow(int r) { return ((r & 3) + ((r >> 2) & 3)) & 3; }

// ---------------- routing: 256 blocks, 16 tokens each (1 wave/token x 4 iters) ----------------
__global__ __launch_bounds__(256) void routing_kernel(
    const float* __restrict__ x, const float* __restrict__ qw,
    const float* __restrict__ kp, const float* __restrict__ vp,
    float* __restrict__ rw_out, int* __restrict__ counts,
    int* __restrict__ list, float2* __restrict__ topw,
    ushort_t* __restrict__ xb)
{
    __shared__ float kp_s[NEXP * HDIM];     // 32 KB
    __shared__ float vp_s[NEXP * NEXP];
    __shared__ int lcnt[NEXP];
    __shared__ int base_s[NEXP];
    __shared__ int tinfo[RBLK][4];          // e0,p0,e1,p1

    int tid = threadIdx.x;
    int wid = tid >> 6, lane = tid & 63;

    if (tid < NEXP) lcnt[tid] = 0;
    if (tid < NEXP * NEXP) vp_s[tid] = vp[tid];
    #pragma unroll
    for (int i = 0; i < 8; i++)
        ((float4*)kp_s)[tid + 256 * i] = ((const float4*)kp)[tid + 256 * i];

    float4 qv[4];
    #pragma unroll
    for (int j = 0; j < 4; j++) qv[j] = ((const float4*)qw)[lane + 64 * j];
    __syncthreads();

    for (int it = 0; it < RBLK / 4; it++) {
        int tl = wid * (RBLK / 4) + it;
        int t = blockIdx.x * RBLK + tl;
        const float4* xr4 = (const float4*)(x + (size_t)t * HDIM);
        float4 xv[4];
        #pragma unroll
        for (int j = 0; j < 4; j++) xv[j] = xr4[lane + 64 * j];

        // fused bf16 conversion of x
        ushort_t* xrow = xb + (size_t)t * HDIM;
        #pragma unroll
        for (int j = 0; j < 4; j++) {
            short4b o;
            o[0] = f2bf(xv[j].x); o[1] = f2bf(xv[j].y);
            o[2] = f2bf(xv[j].z); o[3] = f2bf(xv[j].w);
            ((short4b*)xrow)[lane + 64 * j] = o;
        }

        float ss = 0.f;
        #pragma unroll
        for (int j = 0; j < 4; j++)
            ss += xv[j].x*xv[j].x + xv[j].y*xv[j].y + xv[j].z*xv[j].z + xv[j].w*xv[j].w;
        #pragma unroll
        for (int off = 32; off; off >>= 1) ss += __shfl_xor(ss, off);
        float rms = rsqrtf(ss * (1.0f / HDIM) + 1e-6f);

        float4 q[4];
        #pragma unroll
        for (int j = 0; j < 4; j++) {
            q[j].x = xv[j].x * rms * qv[j].x; q[j].y = xv[j].y * rms * qv[j].y;
            q[j].z = xv[j].z * rms * qv[j].z; q[j].w = xv[j].w * rms * qv[j].w;
        }

        float d[NEXP];
        #pragma unroll
        for (int p = 0; p < NEXP; p++) {
            float acc = 0.f;
            #pragma unroll
            for (int j = 0; j < 4; j++) {
                float4 kv = ((const float4*)kp_s)[p * 256 + lane + 64 * j];
                acc += q[j].x*kv.x + q[j].y*kv.y + q[j].z*kv.z + q[j].w*kv.w;
            }
            #pragma unroll
            for (int off = 32; off; off >>= 1) acc += __shfl_xor(acc, off);
            d[p] = acc * (1.0f / 32.0f);   // /sqrt(1024)
        }

        float m = d[0];
        #pragma unroll
        for (int p = 1; p < NEXP; p++) m = fmaxf(m, d[p]);
        float a[NEXP]; float s = 0.f;
        #pragma unroll
        for (int p = 0; p < NEXP; p++) { a[p] = expf(d[p] - m); s += a[p]; }
        float inv = 1.0f / s;
        #pragma unroll
        for (int p = 0; p < NEXP; p++) a[p] *= inv;
        float lg[NEXP];
        #pragma unroll
        for (int qi = 0; qi < NEXP; qi++) {
            float acc = 0.f;
            #pragma unroll
            for (int p = 0; p < NEXP; p++) acc += a[p] * vp_s[p * NEXP + qi];
            lg[qi] = acc;
        }
        float m2 = lg[0];
        #pragma unroll
        for (int p = 1; p < NEXP; p++) m2 = fmaxf(m2, lg[p]);
        float r[NEXP]; float s2 = 0.f;
        #pragma unroll
        for (int p = 0; p < NEXP; p++) { r[p] = expf(lg[p] - m2); s2 += r[p]; }
        float inv2 = 1.0f / s2;
        #pragma unroll
        for (int p = 0; p < NEXP; p++) r[p] *= inv2;
        int e0 = -1, e1 = -1; float w0 = -1.f, w1 = -1.f;
        #pragma unroll
        for (int p = 0; p < NEXP; p++) {
            if (r[p] > w0) { w1 = w0; e1 = e0; w0 = r[p]; e0 = p; }
            else if (r[p] > w1) { w1 = r[p]; e1 = p; }
        }
        float invn = 1.0f / (w0 + w1 + 1e-9f);
        float w0n = w0 * invn, w1n = w1 * invn;

        if (lane == 0) {
            #pragma unroll
            for (int p = 0; p < NEXP; p++)
                rw_out[(size_t)t * NEXP + p] = (p == e0) ? w0n : ((p == e1) ? w1n : 0.f);
            topw[t] = make_float2(w0n, w1n);
            int p0 = atomicAdd(&lcnt[e0], 1);
            int p1 = atomicAdd(&lcnt[e1], 1);
            tinfo[tl][0] = e0; tinfo[tl][1] = p0;
            tinfo[tl][2] = e1; tinfo[tl][3] = p1;
        }
    }
    __syncthreads();
    if (tid < NEXP) base_s[tid] = atomicAdd(&counts[tid], lcnt[tid]);
    __syncthreads();
    if (tid < RBLK) {
        int t = blockIdx.x * RBLK + tid;
        int e0 = tinfo[tid][0], p0 = tinfo[tid][1];
        int e1 = tinfo[tid][2], p1 = tinfo[tid][3];
        list[e0 * NTOK + base_s[e0] + p0] = t * 2;
        list[e1 * NTOK + base_s[e1] + p1] = t * 2 + 1;
    }
}

// ------- weights: fp32 [E][K][N] -> bf16 tiled [E][N/128][K/32][128][32], swizzle baked -------
// grid (N/64, K/64, E), block 256. tile[r][c*8..] holds source k-granule (c - frow(r))&3.
__global__ __launch_bounds__(256) void conv_t(const float* __restrict__ in, ushort_t* __restrict__ out,
                                              int K, int N) {
    __shared__ ushort_t ts[64][72];
    int e = blockIdx.z;
    int xb = blockIdx.x, yb = blockIdx.y;
    const float* ip = in + (size_t)e * K * N + (size_t)(yb * 64) * N + xb * 64;
    int NB = N / 128, KB2 = K / 32;
    int nb = xb >> 1, rhalf = (xb & 1) * 64;
    ushort_t* opb = out + ((size_t)((size_t)e * NB + nb) * KB2 + yb * 2) * 4096;

    int tid = threadIdx.x;
    int r0 = tid >> 4;            // k-row 0..15
    int c4 = (tid & 15) * 4;      // n-col
    #pragma unroll
    for (int i = 0; i < 4; i++) {
        int r = r0 + i * 16;
        float4 v = *(const float4*)(ip + (size_t)r * N + c4);
        ts[c4+0][r] = f2bf(v.x); ts[c4+1][r] = f2bf(v.y);
        ts[c4+2][r] = f2bf(v.z); ts[c4+3][r] = f2bf(v.w);
    }
    __syncthreads();
    int n = tid >> 2;             // 0..63 local n (row within 128-tile = rhalf + n)
    int kq = (tid & 3) * 16;      // k-offset within 64: granules gk = kq/8, kq/8+1
    int f = frow(n);              // rhalf is a multiple of 64 -> frow(rhalf+n) == frow(n)
    short8 w0 = *(const short8*)&ts[n][kq];
    short8 w1 = *(const short8*)&ts[n][kq + 8];
    int gk0 = kq >> 3, gk1 = gk0 + 1;
    // granule gk: k-tile = yb*2 + (gk>>2), slot c = ((gk&3) + f) & 3
    ushort_t* d0 = opb + (size_t)(gk0 >> 2) * 4096 + (size_t)(rhalf + n) * 32 + (((gk0 & 3) + f) & 3) * 8;
    ushort_t* d1 = opb + (size_t)(gk1 >> 2) * 4096 + (size_t)(rhalf + n) * 32 + (((gk1 & 3) + f) & 3) * 8;
    *(short8*)d0 = w0;
    *(short8*)d1 = w1;
}

// ------- grouped bf16 MFMA GEMM, 128x128 tile, BK=32 (m97 geometry), swizzled LDS -------
// LDS ~17.9 KB -> ~7-8 blocks/CU residency (the latency-hiding lever). Same proven
// 2-barrier loop. A gathered via list; W tiled [E][odim/128][K/32][128][32] pre-swizzled.
// Epilogue: two 64-row passes through a [64][136] bf16 bounce (256B contiguous stores).
template<int K, int FUSED>
__global__ __launch_bounds__(256) void gemm_bf16(
    const ushort_t* __restrict__ A,
    const ushort_t* __restrict__ W0, const ushort_t* __restrict__ W1,
    const int* __restrict__ counts, const int* __restrict__ list,
    ushort_t* __restrict__ out0, ushort_t* __restrict__ out1, int odim)
{
    constexpr int KB = K / 32;
    int e = blockIdx.z;
    int M = counts[e];
    int row0 = blockIdx.y * 128;
    if (row0 >= M) return;
    int nbTiles = odim / 128;
    int colb = blockIdx.x;
    const ushort_t* W = (FUSED && colb >= nbTiles) ? W1 : W0;
    ushort_t* outp    = (FUSED && colb >= nbTiles) ? out1 : out0;
    int nb = (FUSED && colb >= nbTiles) ? colb - nbTiles : colb;
    int col0 = nb * 128;

    __shared__ ushort_t smem[8704];       // staging A[0,4096)+B[4096,8192) / bounce [64][136]
    __shared__ int rowsS[128];
    ushort_t* Abuf = smem;
    ushort_t* Bbuf = smem + 4096;

    int tid = threadIdx.x;
    if (tid < 128) {
        int r = row0 + tid;
        rowsS[tid] = (r < M) ? list[e * NTOK + r] : -1;
    }
    __syncthreads();

    int wid = tid >> 6, lane = tid & 63;
    int wr = wid >> 1, wc = wid & 1;
    int la = lane & 15, lb = lane >> 4;

    // A staging: slot s = i*256+tid covers LDS row s>>2 (i=0: 0..63, i=1: 64..127),
    // granule c = tid&3; source k-granule = (c - frow(row))&3 so LDS stays linear (rule 21).
    int arow = tid >> 2, ac = tid & 3;
    int gsrc = ((ac + 4 - frow(arow)) & 3) * 8;      // frow(row+64) == frow(row)
    const ushort_t* aP[2];
    #pragma unroll
    for (int i = 0; i < 2; i++) {
        int ent = rowsS[i * 64 + arow];
        int tok = (ent >= 0) ? (ent >> 1) : 0;
        aP[i] = A + (size_t)tok * K + gsrc;
    }
    const ushort_t* Wt = W + (size_t)((size_t)e * nbTiles + nb) * ((size_t)KB * 4096);

    // fragment read offsets: lane (la,lb) reads row (..+la), logical granule lb
    int fla = frow(la);
    int aoff[4], boff[4];
    #pragma unroll
    for (int m = 0; m < 4; m++)
        aoff[m] = (wr * 64 + m * 16 + la) * 32 + (((lb + fla) & 3) * 8);
    #pragma unroll
    for (int n = 0; n < 4; n++)
        boff[n] = (wc * 64 + n * 16 + la) * 32 + (((lb + fla) & 3) * 8);

    f32x4 acc[4][4];
    #pragma unroll
    for (int m = 0; m < 4; m++)
        #pragma unroll
        for (int n = 0; n < 4; n++) acc[m][n] = (f32x4){0.f, 0.f, 0.f, 0.f};

    for (int kt = 0; kt < KB; kt++) {
        #pragma unroll
        for (int i = 0; i < 2; i++) {
            __builtin_amdgcn_global_load_lds(GPTR(aP[i] + kt * 32),
                                             LPTR(Abuf + (i * 256 + wid * 64) * 8), 16, 0, 0);
            __builtin_amdgcn_global_load_lds(GPTR(Wt + (size_t)kt * 4096 + (i * 256 + tid) * 8),
                                             LPTR(Bbuf + (i * 256 + wid * 64) * 8), 16, 0, 0);
        }
        __syncthreads();
        short8 af[4], bf[4];
        #pragma unroll
        for (int m = 0; m < 4; m++) af[m] = *(const short8*)&Abuf[aoff[m]];
        #pragma unroll
        for (int n = 0; n < 4; n++) bf[n] = *(const short8*)&Bbuf[boff[n]];
        #pragma unroll
        for (int m = 0; m < 4; m++)
            #pragma unroll
            for (int n = 0; n < 4; n++)
                acc[m][n] = __builtin_amdgcn_mfma_f32_16x16x32_bf16(af[m], bf[n], acc[m][n], 0, 0, 0);
        __syncthreads();
    }
    // trailing __syncthreads guarantees all LDS reads done before bounce reuse

    // epilogue: two 64-row passes through [64][136] bf16 bounce, 256B contiguous row-runs
    ushort_t* ob = smem;
    #pragma unroll
    for (int h = 0; h < 2; h++) {
        __syncthreads();
        if (wr == h) {
            #pragma unroll
            for (int m = 0; m < 4; m++)
                #pragma unroll
                for (int n = 0; n < 4; n++)
                    #pragma unroll
                    for (int j = 0; j < 4; j++)
                        ob[(m * 16 + lb * 4 + j) * 136 + wc * 64 + n * 16 + la] =
                            f2bf(acc[m][n][j]);
        }
        __syncthreads();
        #pragma unroll
        for (int i = 0; i < 4; i++) {
            int slot = i * 256 + tid;      // 64 rows x 16 chunks of 16B
            int rl = slot >> 4, ch = slot & 15;
            int ent = rowsS[h * 64 + rl];
            short8 v = *(const short8*)&ob[rl * 136 + ch * 8];
            if (ent >= 0)
                *(short8*)(outp + (size_t)ent * odim + col0 + ch * 8) = v;
        }
    }
}

// ------- elementwise: mix pairs (bf16 in), silu, write bf16 inter -------
__global__ __launch_bounds__(256) void silu_mix(
    const ushort_t* __restrict__ bg, const ushort_t* __restrict__ bu,
    const float2* __restrict__ topw, ushort_t* __restrict__ inter)
{
    int idx = blockIdx.x * 256 + threadIdx.x;          // over NTOK*IDIM/8
    int t = idx >> 8;                                  // IDIM/8 = 256
    int i8 = (idx & 255) * 8;
    float2 w = topw[t];
    short8 g0 = *(const short8*)(bg + (size_t)(2*t)   * IDIM + i8);
    short8 g1 = *(const short8*)(bg + (size_t)(2*t+1) * IDIM + i8);
    short8 u0 = *(const short8*)(bu + (size_t)(2*t)   * IDIM + i8);
    short8 u1 = *(const short8*)(bu + (size_t)(2*t+1) * IDIM + i8);
    short8 r;
    #pragma unroll
    for (int j = 0; j < 8; j++) {
        float g = w.x * bf2f((ushort_t)g0[j]) + w.y * bf2f((ushort_t)g1[j]);
        float u = w.x * bf2f((ushort_t)u0[j]) + w.y * bf2f((ushort_t)u1[j]);
        float s = g / (1.f + expf(-g)) * u;
        r[j] = f2bf(s);
    }
    *(short8*)(inter + (size_t)t * IDIM + i8) = r;
}

// ------- final: weighted pair reduce (bf16 pout -> fp32 out) -------
__global__ __launch_bounds__(256) void out_mix(
    const ushort_t* __restrict__ pout, const float2* __restrict__ topw,
    float* __restrict__ out)
{
    int idx = blockIdx.x * 256 + threadIdx.x;          // over NTOK*HDIM/8
    int t = idx >> 7;                                  // HDIM/8 = 128
    int h8 = (idx & 127) * 8;
    float2 w = topw[t];
    short8 a = *(const short8*)(pout + (size_t)(2*t)   * HDIM + h8);
    short8 b = *(const short8*)(pout + (size_t)(2*t+1) * HDIM + h8);
    float4 r0, r1;
    r0.x = w.x*bf2f((ushort_t)a[0]) + w.y*bf2f((ushort_t)b[0]);
    r0.y = w.x*bf2f((ushort_t)a[1]) + w.y*bf2f((ushort_t)b[1]);
    r0.z = w.x*bf2f((ushort_t)a[2]) + w.y*bf2f((ushort_t)b[2]);
    r0.w = w.x*bf2f((ushort_t)a[3]) + w.y*bf2f((ushort_t)b[3]);
    r1.x = w.x*bf2f((ushort_t)a[4]) + w.y*bf2f((ushort_t)b[4]);
    r1.y = w.x*bf2f((ushort_t)a[5]) + w.y*bf2f((ushort_t)b[5]);
    r1.z = w.x*bf2f((ushort_t)a[6]) + w.y*bf2f((ushort_t)b[6]);
    r1.w = w.x*bf2f((ushort_t)a[7]) + w.y*bf2f((ushort_t)b[7]);
    float* op = out + (size_t)t * HDIM + h8;
    *(float4*)op       = r0;
    *(float4*)(op + 4) = r1;
}

extern "C" void kernel_launch(void* const* d_in, const int* in_sizes, int n_in,
                              void* d_out, int out_size, void* d_ws, size_t ws_size,
                              hipStream_t stream) {
    const float* x    = (const float*)d_in[0];
    const float* qw   = (const float*)d_in[1];
    const float* kp   = (const float*)d_in[2];
    const float* vp   = (const float*)d_in[3];
    const float* gate = (const float*)d_in[4];
    const float* up   = (const float*)d_in[5];
    const float* down = (const float*)d_in[6];
    float* out = (float*)d_out;
    float* rw_out = out + (size_t)NTOK * HDIM;

    char* ws = (char*)d_ws;
    int*      counts = (int*)ws;                          // 32 B
    float2*   topw   = (float2*)(ws + 1024);              // 32 KB
    int*      list   = (int*)(ws + 64 * 1024);            // 128 KB
    ushort_t* xb     = (ushort_t*)(ws + 256 * 1024);      // 8 MB
    ushort_t* wtg    = xb + (size_t)NTOK * HDIM;          // 32 MB (tiled bf16)
    ushort_t* wtu    = wtg + (size_t)NEXP * HDIM * IDIM;  // 32 MB
    ushort_t* wtd    = wtu + (size_t)NEXP * HDIM * IDIM;  // 32 MB
    ushort_t* bg     = wtd + (size_t)NEXP * HDIM * IDIM;  // 33.5 MB (bf16 [8192 ents][I])
    ushort_t* bu     = bg  + (size_t)2 * NTOK * IDIM;     // 33.5 MB
    ushort_t* interb = bu  + (size_t)2 * NTOK * IDIM;     // 16.8 MB (bf16 [NTOK][I])
    ushort_t* pout   = bg;   // alias: bf16 [8192 ents][HDIM] = 16.8 MB (bg dead after silu_mix)

    hipMemsetAsync(counts, 0, NEXP * sizeof(int), stream);

    routing_kernel<<<NTOK / RBLK, 256, 0, stream>>>(x, qw, kp, vp, rw_out, counts, list, topw, xb);

    conv_t<<<dim3(IDIM / 64, HDIM / 64, NEXP), 256, 0, stream>>>(gate, wtg, HDIM, IDIM);
    conv_t<<<dim3(IDIM / 64, HDIM / 64, NEXP), 256, 0, stream>>>(up,   wtu, HDIM, IDIM);
    conv_t<<<dim3(HDIM / 64, IDIM / 64, NEXP), 256, 0, stream>>>(down, wtd, IDIM, HDIM);

    // fused gate+up: cols 0..2047 gate, 2048..4095 up
    dim3 ggu(2 * IDIM / 128, NTOK / 128, NEXP);   // (32, 32, 8)
    gemm_bf16<HDIM, 1><<<ggu, 256, 0, stream>>>(xb, wtg, wtu, counts, list, bg, bu, IDIM);

    silu_mix<<<NTOK * IDIM / 8 / 256, 256, 0, stream>>>(bg, bu, topw, interb);

    dim3 gd(HDIM / 128, NTOK / 128, NEXP);        // (8, 32, 8)
    gemm_bf16<IDIM, 0><<<gd, 256, 0, stream>>>(interb, wtd, (const ushort_t*)nullptr,
                                               counts, list, pout, nullptr, HDIM);

    out_mix<<<NTOK * HDIM / 8 / 256, 256, 0, stream>>>(pout, topw, out);
}

// Round 16
// 248.119 us; speedup vs baseline: 1.3899x; 1.3899x over previous
//
#include <hip/hip_runtime.h>
#include <hip/hip_bf16.h>

#define NTOK 4096   // B*T
#define HDIM 1024
#define IDIM 2048
#define NEXP 8
#define RBLK 16     // tokens per routing block

typedef __attribute__((ext_vector_type(8))) short short8;
typedef __attribute__((ext_vector_type(4))) short short4b;
typedef __attribute__((ext_vector_type(4))) float f32x4;
typedef unsigned short ushort_t;

__device__ inline ushort_t f2bf(float f) {
    union { float f; unsigned u; } v; v.f = f;
    unsigned r = v.u + 0x7FFFu + ((v.u >> 16) & 1u);
    return (ushort_t)(r >> 16);
}
__device__ inline float bf2f(ushort_t h) {
    union { unsigned u; float f; } v; v.u = ((unsigned)h) << 16;
    return v.f;
}

#define GPTR(p) ((const __attribute__((address_space(1))) void*)(p))
#define LPTR(p) ((__attribute__((address_space(3))) void*)(p))

// ---------------- routing: 256 blocks, 16 tokens each (1 wave/token x 4 iters) ----------------
__global__ __launch_bounds__(256) void routing_kernel(
    const float* __restrict__ x, const float* __restrict__ qw,
    const float* __restrict__ kp, const float* __restrict__ vp,
    float* __restrict__ rw_out, int* __restrict__ counts,
    int* __restrict__ list, float2* __restrict__ topw,
    ushort_t* __restrict__ xb)
{
    __shared__ float kp_s[NEXP * HDIM];     // 32 KB
    __shared__ float vp_s[NEXP * NEXP];
    __shared__ int lcnt[NEXP];
    __shared__ int base_s[NEXP];
    __shared__ int tinfo[RBLK][4];          // e0,p0,e1,p1

    int tid = threadIdx.x;
    int wid = tid >> 6, lane = tid & 63;

    if (tid < NEXP) lcnt[tid] = 0;
    if (tid < NEXP * NEXP) vp_s[tid] = vp[tid];
    #pragma unroll
    for (int i = 0; i < 8; i++)
        ((float4*)kp_s)[tid + 256 * i] = ((const float4*)kp)[tid + 256 * i];

    float4 qv[4];
    #pragma unroll
    for (int j = 0; j < 4; j++) qv[j] = ((const float4*)qw)[lane + 64 * j];
    __syncthreads();

    for (int it = 0; it < RBLK / 4; it++) {
        int tl = wid * (RBLK / 4) + it;
        int t = blockIdx.x * RBLK + tl;
        const float4* xr4 = (const float4*)(x + (size_t)t * HDIM);
        float4 xv[4];
        #pragma unroll
        for (int j = 0; j < 4; j++) xv[j] = xr4[lane + 64 * j];

        // fused bf16 conversion of x
        ushort_t* xrow = xb + (size_t)t * HDIM;
        #pragma unroll
        for (int j = 0; j < 4; j++) {
            short4b o;
            o[0] = f2bf(xv[j].x); o[1] = f2bf(xv[j].y);
            o[2] = f2bf(xv[j].z); o[3] = f2bf(xv[j].w);
            ((short4b*)xrow)[lane + 64 * j] = o;
        }

        float ss = 0.f;
        #pragma unroll
        for (int j = 0; j < 4; j++)
            ss += xv[j].x*xv[j].x + xv[j].y*xv[j].y + xv[j].z*xv[j].z + xv[j].w*xv[j].w;
        #pragma unroll
        for (int off = 32; off; off >>= 1) ss += __shfl_xor(ss, off);
        float rms = rsqrtf(ss * (1.0f / HDIM) + 1e-6f);

        float4 q[4];
        #pragma unroll
        for (int j = 0; j < 4; j++) {
            q[j].x = xv[j].x * rms * qv[j].x; q[j].y = xv[j].y * rms * qv[j].y;
            q[j].z = xv[j].z * rms * qv[j].z; q[j].w = xv[j].w * rms * qv[j].w;
        }

        float d[NEXP];
        #pragma unroll
        for (int p = 0; p < NEXP; p++) {
            float acc = 0.f;
            #pragma unroll
            for (int j = 0; j < 4; j++) {
                float4 kv = ((const float4*)kp_s)[p * 256 + lane + 64 * j];
                acc += q[j].x*kv.x + q[j].y*kv.y + q[j].z*kv.z + q[j].w*kv.w;
            }
            #pragma unroll
            for (int off = 32; off; off >>= 1) acc += __shfl_xor(acc, off);
            d[p] = acc * (1.0f / 32.0f);   // /sqrt(1024)
        }

        float m = d[0];
        #pragma unroll
        for (int p = 1; p < NEXP; p++) m = fmaxf(m, d[p]);
        float a[NEXP]; float s = 0.f;
        #pragma unroll
        for (int p = 0; p < NEXP; p++) { a[p] = expf(d[p] - m); s += a[p]; }
        float inv = 1.0f / s;
        #pragma unroll
        for (int p = 0; p < NEXP; p++) a[p] *= inv;
        float lg[NEXP];
        #pragma unroll
        for (int qi = 0; qi < NEXP; qi++) {
            float acc = 0.f;
            #pragma unroll
            for (int p = 0; p < NEXP; p++) acc += a[p] * vp_s[p * NEXP + qi];
            lg[qi] = acc;
        }
        float m2 = lg[0];
        #pragma unroll
        for (int p = 1; p < NEXP; p++) m2 = fmaxf(m2, lg[p]);
        float r[NEXP]; float s2 = 0.f;
        #pragma unroll
        for (int p = 0; p < NEXP; p++) { r[p] = expf(lg[p] - m2); s2 += r[p]; }
        float inv2 = 1.0f / s2;
        #pragma unroll
        for (int p = 0; p < NEXP; p++) r[p] *= inv2;
        int e0 = -1, e1 = -1; float w0 = -1.f, w1 = -1.f;
        #pragma unroll
        for (int p = 0; p < NEXP; p++) {
            if (r[p] > w0) { w1 = w0; e1 = e0; w0 = r[p]; e0 = p; }
            else if (r[p] > w1) { w1 = r[p]; e1 = p; }
        }
        float invn = 1.0f / (w0 + w1 + 1e-9f);
        float w0n = w0 * invn, w1n = w1 * invn;

        if (lane == 0) {
            #pragma unroll
            for (int p = 0; p < NEXP; p++)
                rw_out[(size_t)t * NEXP + p] = (p == e0) ? w0n : ((p == e1) ? w1n : 0.f);
            topw[t] = make_float2(w0n, w1n);
            int p0 = atomicAdd(&lcnt[e0], 1);
            int p1 = atomicAdd(&lcnt[e1], 1);
            tinfo[tl][0] = e0; tinfo[tl][1] = p0;
            tinfo[tl][2] = e1; tinfo[tl][3] = p1;
        }
    }
    __syncthreads();
    if (tid < NEXP) base_s[tid] = atomicAdd(&counts[tid], lcnt[tid]);
    __syncthreads();
    if (tid < RBLK) {
        int t = blockIdx.x * RBLK + tid;
        int e0 = tinfo[tid][0], p0 = tinfo[tid][1];
        int e1 = tinfo[tid][2], p1 = tinfo[tid][3];
        list[e0 * NTOK + base_s[e0] + p0] = t * 2;
        list[e1 * NTOK + base_s[e1] + p1] = t * 2 + 1;
    }
}

// ------- weights: fp32 [E][K][N] -> bf16 tiled [E][N/128][K/64][128][64], bank-swizzle baked -------
// grid (N/64, K/64, E), block 256. Tile[r][c] = bf16(in[k = kb*64 + (c ^ ((r&7)<<3))][n = nb*128 + r])
__global__ __launch_bounds__(256) void conv_t(const float* __restrict__ in, ushort_t* __restrict__ out,
                                              int K, int N) {
    __shared__ ushort_t ts[64][72];
    int e = blockIdx.z;
    int xb = blockIdx.x, yb = blockIdx.y;
    const float* ip = in + (size_t)e * K * N + (size_t)(yb * 64) * N + xb * 64;
    int NB = N / 128, KB = K / 64;
    int nb = xb >> 1, rhalf = (xb & 1) * 64;
    ushort_t* op = out + ((size_t)((size_t)e * NB + nb) * KB + yb) * (128 * 64);

    int tid = threadIdx.x;
    int r0 = tid >> 4;            // k-row 0..15
    int c4 = (tid & 15) * 4;      // n-col
    #pragma unroll
    for (int i = 0; i < 4; i++) {
        int r = r0 + i * 16;
        float4 v = *(const float4*)(ip + (size_t)r * N + c4);
        ts[c4+0][r] = f2bf(v.x); ts[c4+1][r] = f2bf(v.y);
        ts[c4+2][r] = f2bf(v.z); ts[c4+3][r] = f2bf(v.w);
    }
    __syncthreads();
    int n = tid >> 2;             // 0..63 local n
    int kq = (tid & 3) * 16;
    int sw = (n & 7) << 3;        // ushort xor (row&7 within tile; rhalf is mult of 64)
    short8 w0 = *(const short8*)&ts[n][kq];
    short8 w1 = *(const short8*)&ts[n][kq + 8];
    ushort_t* dst = op + (size_t)(rhalf + n) * 64;
    *(short8*)(dst + (kq ^ sw))       = w0;
    *(short8*)(dst + ((kq + 8) ^ sw)) = w1;
}

// ------- grouped bf16 MFMA GEMM, 128x128 tile, BK=64, swizzled LDS, coalesced staging -------
// A gathered via list (token-major, K wide). Output bf16 at ent-major rows, via LDS bounce
// so HBM writes are contiguous 256B row-runs. W tiled [E][odim/128][K/64][128][64], swizzled.
template<int K, int FUSED>
__global__ __launch_bounds__(256) void gemm_bf16(
    const ushort_t* __restrict__ A,
    const ushort_t* __restrict__ W0, const ushort_t* __restrict__ W1,
    const int* __restrict__ counts, const int* __restrict__ list,
    ushort_t* __restrict__ out0, ushort_t* __restrict__ out1, int odim)
{
    constexpr int KB = K / 64;
    int e = blockIdx.z;
    int M = counts[e];
    int row0 = blockIdx.y * 128;
    if (row0 >= M) return;
    int nbTiles = odim / 128;
    int colb = blockIdx.x;
    const ushort_t* W = (FUSED && colb >= nbTiles) ? W1 : W0;
    ushort_t* outp    = (FUSED && colb >= nbTiles) ? out1 : out0;
    int nb = (FUSED && colb >= nbTiles) ? colb - nbTiles : colb;
    int col0 = nb * 128;

    __shared__ ushort_t smem[128 * 136];  // staging (32KB) + epilogue bounce (union)
    __shared__ int rowsS[128];
    ushort_t* Abuf = smem;
    ushort_t* Bbuf = smem + 8192;

    int tid = threadIdx.x;
    if (tid < 128) {
        int r = row0 + tid;
        rowsS[tid] = (r < M) ? list[e * NTOK + r] : -1;
    }
    __syncthreads();

    int wid = tid >> 6, lane = tid & 63;
    int wr = wid >> 1, wc = wid & 1;
    int la = lane & 15, lb = lane >> 4;

    // A staging: seg = wid*4+i covers rows seg*8..+7; lane -> row seg*8+(lane>>3),
    // 16B chunk (lane&7), source k pre-swizzled so LDS stays linear (rule 21 / m173).
    int swu = (((lane & 7) ^ (lane >> 3)) * 8);
    const ushort_t* aP[4];
    #pragma unroll
    for (int i = 0; i < 4; i++) {
        int r = (wid * 4 + i) * 8 + (lane >> 3);
        int ent = rowsS[r];
        int tok = (ent >= 0) ? (ent >> 1) : 0;
        aP[i] = A + (size_t)tok * K + swu;
    }
    const ushort_t* Wt = W + (size_t)((size_t)e * nbTiles + nb) * ((size_t)KB * 8192);

    int swr = (la & 7) << 3;
    int aoff[4][2], boff[4][2];
    #pragma unroll
    for (int m = 0; m < 4; m++)
        #pragma unroll
        for (int ks = 0; ks < 2; ks++)
            aoff[m][ks] = (wr * 64 + m * 16 + la) * 64 + ((ks * 32 + lb * 8) ^ swr);
    #pragma unroll
    for (int n = 0; n < 4; n++)
        #pragma unroll
        for (int ks = 0; ks < 2; ks++)
            boff[n][ks] = (wc * 64 + n * 16 + la) * 64 + ((ks * 32 + lb * 8) ^ swr);

    f32x4 acc[4][4];
    #pragma unroll
    for (int m = 0; m < 4; m++)
        #pragma unroll
        for (int n = 0; n < 4; n++) acc[m][n] = (f32x4){0.f, 0.f, 0.f, 0.f};

    for (int kt = 0; kt < KB; kt++) {
        #pragma unroll
        for (int i = 0; i < 4; i++) {
            int seg = wid * 4 + i;
            __builtin_amdgcn_global_load_lds(GPTR(aP[i] + kt * 64),
                                             LPTR(Abuf + seg * 512), 16, 0, 0);
            __builtin_amdgcn_global_load_lds(GPTR(Wt + (size_t)kt * 8192 + seg * 512 + lane * 8),
                                             LPTR(Bbuf + seg * 512), 16, 0, 0);
        }
        __syncthreads();
        #pragma unroll
        for (int ks = 0; ks < 2; ks++) {
            short8 af[4], bf[4];
            #pragma unroll
            for (int m = 0; m < 4; m++) af[m] = *(const short8*)&Abuf[aoff[m][ks]];
            #pragma unroll
            for (int n = 0; n < 4; n++) bf[n] = *(const short8*)&Bbuf[boff[n][ks]];
            #pragma unroll
            for (int m = 0; m < 4; m++)
                #pragma unroll
                for (int n = 0; n < 4; n++)
                    acc[m][n] = __builtin_amdgcn_mfma_f32_16x16x32_bf16(af[m], bf[n], acc[m][n], 0, 0, 0);
        }
        __syncthreads();
    }
    // trailing __syncthreads guarantees all LDS reads done before bounce reuse

    // epilogue: scatter acc -> [128][136] bf16 bounce, flush 256B contiguous row-runs
    ushort_t* ob = smem;
    #pragma unroll
    for (int m = 0; m < 4; m++)
        #pragma unroll
        for (int n = 0; n < 4; n++)
            #pragma unroll
            for (int j = 0; j < 4; j++)
                ob[(wr * 64 + m * 16 + lb * 4 + j) * 136 + wc * 64 + n * 16 + la] =
                    f2bf(acc[m][n][j]);
    __syncthreads();
    int ch = tid & 15, rg = tid >> 4;       // 16 chunks x 16B = 128 cols
    #pragma unroll
    for (int i = 0; i < 8; i++) {
        int r = i * 16 + rg;
        int ent = rowsS[r];
        short8 v = *(const short8*)&ob[r * 136 + ch * 8];
        if (ent >= 0)
            *(short8*)(outp + (size_t)ent * odim + col0 + ch * 8) = v;
    }
}

// ------- elementwise: mix pairs (bf16 in), silu, write bf16 inter -------
__global__ __launch_bounds__(256) void silu_mix(
    const ushort_t* __restrict__ bg, const ushort_t* __restrict__ bu,
    const float2* __restrict__ topw, ushort_t* __restrict__ inter)
{
    int idx = blockIdx.x * 256 + threadIdx.x;          // over NTOK*IDIM/8
    int t = idx >> 8;                                  // IDIM/8 = 256
    int i8 = (idx & 255) * 8;
    float2 w = topw[t];
    short8 g0 = *(const short8*)(bg + (size_t)(2*t)   * IDIM + i8);
    short8 g1 = *(const short8*)(bg + (size_t)(2*t+1) * IDIM + i8);
    short8 u0 = *(const short8*)(bu + (size_t)(2*t)   * IDIM + i8);
    short8 u1 = *(const short8*)(bu + (size_t)(2*t+1) * IDIM + i8);
    short8 r;
    #pragma unroll
    for (int j = 0; j < 8; j++) {
        float g = w.x * bf2f((ushort_t)g0[j]) + w.y * bf2f((ushort_t)g1[j]);
        float u = w.x * bf2f((ushort_t)u0[j]) + w.y * bf2f((ushort_t)u1[j]);
        float s = g / (1.f + expf(-g)) * u;
        r[j] = f2bf(s);
    }
    *(short8*)(inter + (size_t)t * IDIM + i8) = r;
}

// ------- final: weighted pair reduce (bf16 pout -> fp32 out) -------
__global__ __launch_bounds__(256) void out_mix(
    const ushort_t* __restrict__ pout, const float2* __restrict__ topw,
    float* __restrict__ out)
{
    int idx = blockIdx.x * 256 + threadIdx.x;          // over NTOK*HDIM/8
    int t = idx >> 7;                                  // HDIM/8 = 128
    int h8 = (idx & 127) * 8;
    float2 w = topw[t];
    short8 a = *(const short8*)(pout + (size_t)(2*t)   * HDIM + h8);
    short8 b = *(const short8*)(pout + (size_t)(2*t+1) * HDIM + h8);
    float4 r0, r1;
    r0.x = w.x*bf2f((ushort_t)a[0]) + w.y*bf2f((ushort_t)b[0]);
    r0.y = w.x*bf2f((ushort_t)a[1]) + w.y*bf2f((ushort_t)b[1]);
    r0.z = w.x*bf2f((ushort_t)a[2]) + w.y*bf2f((ushort_t)b[2]);
    r0.w = w.x*bf2f((ushort_t)a[3]) + w.y*bf2f((ushort_t)b[3]);
    r1.x = w.x*bf2f((ushort_t)a[4]) + w.y*bf2f((ushort_t)b[4]);
    r1.y = w.x*bf2f((ushort_t)a[5]) + w.y*bf2f((ushort_t)b[5]);
    r1.z = w.x*bf2f((ushort_t)a[6]) + w.y*bf2f((ushort_t)b[6]);
    r1.w = w.x*bf2f((ushort_t)a[7]) + w.y*bf2f((ushort_t)b[7]);
    float* op = out + (size_t)t * HDIM + h8;
    *(float4*)op       = r0;
    *(float4*)(op + 4) = r1;
}

extern "C" void kernel_launch(void* const* d_in, const int* in_sizes, int n_in,
                              void* d_out, int out_size, void* d_ws, size_t ws_size,
                              hipStream_t stream) {
    const float* x    = (const float*)d_in[0];
    const float* qw   = (const float*)d_in[1];
    const float* kp   = (const float*)d_in[2];
    const float* vp   = (const float*)d_in[3];
    const float* gate = (const float*)d_in[4];
    const float* up   = (const float*)d_in[5];
    const float* down = (const float*)d_in[6];
    float* out = (float*)d_out;
    float* rw_out = out + (size_t)NTOK * HDIM;

    char* ws = (char*)d_ws;
    int*      counts = (int*)ws;                          // 32 B
    float2*   topw   = (float2*)(ws + 1024);              // 32 KB
    int*      list   = (int*)(ws + 64 * 1024);            // 128 KB
    ushort_t* xb     = (ushort_t*)(ws + 256 * 1024);      // 8 MB
    ushort_t* wtg    = xb + (size_t)NTOK * HDIM;          // 32 MB (tiled bf16)
    ushort_t* wtu    = wtg + (size_t)NEXP * HDIM * IDIM;  // 32 MB
    ushort_t* wtd    = wtu + (size_t)NEXP * HDIM * IDIM;  // 32 MB
    ushort_t* bg     = wtd + (size_t)NEXP * HDIM * IDIM;  // 33.5 MB (bf16 [8192 ents][I])
    ushort_t* bu     = bg  + (size_t)2 * NTOK * IDIM;     // 33.5 MB
    ushort_t* interb = bu  + (size_t)2 * NTOK * IDIM;     // 16.8 MB (bf16 [NTOK][I])
    ushort_t* pout   = bg;   // alias: bf16 [8192 ents][HDIM] = 16.8 MB (bg dead after silu_mix)

    hipMemsetAsync(counts, 0, NEXP * sizeof(int), stream);

    routing_kernel<<<NTOK / RBLK, 256, 0, stream>>>(x, qw, kp, vp, rw_out, counts, list, topw, xb);

    conv_t<<<dim3(IDIM / 64, HDIM / 64, NEXP), 256, 0, stream>>>(gate, wtg, HDIM, IDIM);
    conv_t<<<dim3(IDIM / 64, HDIM / 64, NEXP), 256, 0, stream>>>(up,   wtu, HDIM, IDIM);
    conv_t<<<dim3(HDIM / 64, IDIM / 64, NEXP), 256, 0, stream>>>(down, wtd, IDIM, HDIM);

    // fused gate+up: cols 0..2047 gate, 2048..4095 up
    dim3 ggu(2 * IDIM / 128, NTOK / 128, NEXP);   // (32, 32, 8)
    gemm_bf16<HDIM, 1><<<ggu, 256, 0, stream>>>(xb, wtg, wtu, counts, list, bg, bu, IDIM);

    silu_mix<<<NTOK * IDIM / 8 / 256, 256, 0, stream>>>(bg, bu, topw, interb);

    dim3 gd(HDIM / 128, NTOK / 128, NEXP);        // (8, 32, 8)
    gemm_bf16<IDIM, 0><<<gd, 256, 0, stream>>>(interb, wtd, (const ushort_t*)nullptr,
                                               counts, list, pout, nullptr, HDIM);

    out_mix<<<NTOK * HDIM / 8 / 256, 256, 0, stream>>>(pout, topw, out);
}